// Round 5
// baseline (106.015 us; speedup 1.0000x reference)
//
#include <hip/hip_runtime.h>
#include <math.h>

#define BB 8
#define HH 16
#define NN 1024
#define TB 128                 // 2 waves per block
#define POWN 4                 // own points per thread
#define HALF 512               // own points per block (TB * POWN)
#define SUBS 4                 // pass{A,B} x half{0,1}

// ws: ws[blk] = partial sde sum, blk = bh*SUBS + sub. 512 floats, all written.

// ---------------------------------------------------------------------------
// chamfer: block (bh, pass, half). Own side: 4 pts/thread in registers,
// coords premultiplied by -2 (mx,my,mz) so the pair kernel is
//   key = fma(mx,qx, fma(my,qy, fma(mz,qz, q.sq)))   (3 fma + 1 fmin)
// Scan side: all 1024 opposing points in LDS as float4{x,y,z,sq}; one
// broadcast ds_read_b128 feeds 16 VALU ops (4 own points).
// Pass A: own=reflected, scan=samples (row mins). Pass B: own=samples,
// scan=reflected (col mins). Block writes one float: sum of its 512 mins.
// ---------------------------------------------------------------------------
__global__ __launch_bounds__(TB) void chamfer_kernel(
    const float* __restrict__ y_pred,
    const float* __restrict__ sp,
    float* __restrict__ ws)
{
    __shared__ __align__(16) float4 pts[NN];     // 16 KB
    __shared__ float wsum[TB / 64];

    const int blk   = blockIdx.x;
    const int bh    = blk >> 2;
    const int sub   = blk & 3;
    const int passB = sub >> 1;          // 0: own=refl scan=samples
    const int half  = sub & 1;
    const int b     = bh >> 4;           // HH = 16
    const int tid   = threadIdx.x;

    float pnx = y_pred[bh * 4 + 0];
    float pny = y_pred[bh * 4 + 1];
    float pnz = y_pred[bh * 4 + 2];
    float pd  = y_pred[bh * 4 + 3];
    float inv = 1.0f / sqrtf(pnx * pnx + pny * pny + pnz * pnz);
    pnx *= inv; pny *= inv; pnz *= inv;

    const float* spb = sp + (size_t)b * NN * 3;

    // stage the SCAN side (all 1024 points)
    for (int p = tid; p < NN; p += TB) {
        float x = spb[p * 3 + 0];
        float y = spb[p * 3 + 1];
        float z = spb[p * 3 + 2];
        if (passB) {
            float proj = x * pnx + y * pny + z * pnz + pd;
            x -= 2.0f * proj * pnx;
            y -= 2.0f * proj * pny;
            z -= 2.0f * proj * pnz;
        }
        pts[p] = make_float4(x, y, z, x * x + y * y + z * z);
    }

    // own points (registers), coords pre-scaled by -2
    float mx[POWN], my[POWN], mz[POWN], osq[POWN];
    for (int k = 0; k < POWN; ++k) {
        const int pidx = half * HALF + k * TB + tid;
        float x = spb[pidx * 3 + 0];
        float y = spb[pidx * 3 + 1];
        float z = spb[pidx * 3 + 2];
        if (!passB) {
            float proj = x * pnx + y * pny + z * pnz + pd;
            x -= 2.0f * proj * pnx;
            y -= 2.0f * proj * pny;
            z -= 2.0f * proj * pnz;
        }
        osq[k] = x * x + y * y + z * z;
        mx[k] = -2.0f * x; my[k] = -2.0f * y; mz[k] = -2.0f * z;
    }
    __syncthreads();

    float m0[POWN], m1[POWN];
    for (int k = 0; k < POWN; ++k) { m0[k] = 3.4e38f; m1[k] = 3.4e38f; }

    // 2-way unrolled scan: 2 broadcast b128 loads + 32 VALU per iteration
    for (int j = 0; j < NN; j += 2) {
        float4 qa = pts[j + 0];
        float4 qb = pts[j + 1];
#pragma unroll
        for (int k = 0; k < POWN; ++k) {
            m0[k] = fminf(m0[k], fmaf(mx[k], qa.x, fmaf(my[k], qa.y, fmaf(mz[k], qa.z, qa.w))));
            m1[k] = fminf(m1[k], fmaf(mx[k], qb.x, fmaf(my[k], qb.y, fmaf(mz[k], qb.z, qb.w))));
        }
    }

    float local = 0.0f;
    for (int k = 0; k < POWN; ++k) local += osq[k] + fminf(m0[k], m1[k]);

    // block sum (2 waves) -> ws[blk]
    for (int off = 32; off; off >>= 1) local += __shfl_down(local, off, 64);
    if ((tid & 63) == 0) wsum[tid >> 6] = local;
    __syncthreads();
    if (tid == 0) ws[blk] = wsum[0] + wsum[1];
}

// ---------------------------------------------------------------------------
// finalize: per batch — centroid, sde from 4 partials per (b,h), conf,
// angle-NMS, stable rank, output write.
// ---------------------------------------------------------------------------
__global__ __launch_bounds__(64) void finalize_kernel(
    const float* __restrict__ ws,
    const float* __restrict__ y_pred,
    const float* __restrict__ sp,
    float* __restrict__ out)
{
    const int b   = blockIdx.x;
    const int tid = threadIdx.x;

    const float* spb = sp + (size_t)b * NN * 3;
    float sx = 0.0f, sy = 0.0f, sz = 0.0f;
    for (int p = tid; p < NN; p += 64) {
        sx += spb[p * 3 + 0];
        sy += spb[p * 3 + 1];
        sz += spb[p * 3 + 2];
    }
    for (int off = 32; off; off >>= 1) {
        sx += __shfl_down(sx, off, 64);
        sy += __shfl_down(sy, off, 64);
        sz += __shfl_down(sz, off, 64);
    }
    sx = __shfl(sx, 0, 64); sy = __shfl(sy, 0, 64); sz = __shfl(sz, 0, 64);
    const float cmx = sx / NN, cmy = sy / NN, cmz = sz / NN;

    __shared__ float sde_s[HH], nx_s[HH], ny_s[HH], nz_s[HH], d_s[HH], conf_s[HH];
    __shared__ int keep_s[HH];

    if (tid < HH) {
        int h = tid;
        float nx = y_pred[(b * HH + h) * 4 + 0];
        float ny = y_pred[(b * HH + h) * 4 + 1];
        float nz = y_pred[(b * HH + h) * 4 + 2];
        float d  = y_pred[(b * HH + h) * 4 + 3];
        float inv = 1.0f / sqrtf(nx * nx + ny * ny + nz * nz);
        nx *= inv; ny *= inv; nz *= inv;
        nx_s[h] = nx; ny_s[h] = ny; nz_s[h] = nz; d_s[h] = d;
        const float* wp = ws + (size_t)(b * HH + h) * SUBS;
        sde_s[h] = (wp[0] + wp[1] + wp[2] + wp[3]) * (1.0f / NN);
    }
    __syncthreads();

    if (tid < HH) {
        int h = tid;
        float mn = sde_s[0], mx = sde_s[0];
        for (int g = 1; g < HH; ++g) {
            mn = fminf(mn, sde_s[g]);
            mx = fmaxf(mx, sde_s[g]);
        }
        float sde  = sde_s[h];
        float conf = 1.0f - (sde - mn) / fabsf(mx - mn);
        conf_s[h]  = conf;
        bool valid = (sde <= 10.0f);
        bool sup   = false;
        if (valid) {
            for (int g = 0; g < HH; ++g) {
                if (g == h) continue;
                float c = nx_s[h] * nx_s[g] + ny_s[h] * ny_s[g] + nz_s[h] * nz_s[g];
                c = fminf(1.0f, fmaxf(-1.0f, c));
                float ang = acosf(c) * 57.29577951308232f;
                bool close = (ang < 30.0f) || (180.0f - ang < 30.0f);
                if (close && (sde_s[g] <= 10.0f) && (sde >= sde_s[g])) sup = true;
            }
        }
        keep_s[h] = (valid && !sup) ? 1 : 0;
    }
    __syncthreads();

    if (tid < HH) {
        int h = tid;
        // stable descending rank on key = keep ? conf : -inf (jnp.argsort(-key))
        float keyh = keep_s[h] ? conf_s[h] : -INFINITY;
        int pos = 0;
        for (int g = 0; g < HH; ++g) {
            float keyg = keep_s[g] ? conf_s[g] : -INFINITY;
            if (keyg > keyh || (keyg == keyh && g < h)) ++pos;
        }
        float nx = nx_s[h], ny = ny_s[h], nz = nz_s[h];
        float t  = nx * cmx + ny * cmy + nz * cmz + d_s[h];
        float px = cmx - t * nx, py = cmy - t * ny, pz = cmz - t * nz;

        float* o = out + (size_t)(b * HH + pos) * 8;
        if (keep_s[h]) {
            o[0] = nx; o[1] = ny; o[2] = nz;
            o[3] = px; o[4] = py; o[5] = pz;
            o[6] = conf_s[h];
            o[7] = sde_s[h];
        } else {
            for (int c = 0; c < 8; ++c) o[c] = 0.0f;
        }
    }
}

extern "C" void kernel_launch(void* const* d_in, const int* in_sizes, int n_in,
                              void* d_out, int out_size, void* d_ws, size_t ws_size,
                              hipStream_t stream) {
    const float* y_pred = (const float*)d_in[0];   // (8,16,4) f32
    const float* sp     = (const float*)d_in[1];   // (8,1024,3) f32
    float* out          = (float*)d_out;           // (8,16,8) f32
    float* ws           = (float*)d_ws;            // 512 floats, all written

    chamfer_kernel<<<dim3(BB * HH * SUBS), dim3(TB), 0, stream>>>(y_pred, sp, ws);
    finalize_kernel<<<dim3(BB), dim3(64), 0, stream>>>(ws, y_pred, sp, out);
}

// Round 6
// 78.082 us; speedup vs baseline: 1.3577x; 1.3577x over previous
//
#include <hip/hip_runtime.h>
#include <math.h>

#define BB 8
#define HH 16
#define NN 1024
#define TB 256
#define POWN 2          // own points per thread
#define OCH 512         // own points per block
#define SCH 512         // scan points per block (half of NN)

// ws layout (floats): partial row-mins
//   part[(bh*2 + sh)*NN + i] = min over scan-half sh of key(i, j)  (+ own_sq)
// 128*2*1024 = 262144 floats = 1 MB. Every slot written exactly once.

// ---------------------------------------------------------------------------
// chamfer: ONLY pass A is computed. By the reflection-isometry identity,
//   sum_j min_i d2[i,j] == sum_i min_j d2[i,j],  so sde = 2*mean_i min_j d2.
// Block (bh, oh, sh): own = reflected points [oh*512, +512) (POWN=2/thread,
// coords pre-scaled by -2), scan = raw samples [sh*512, +512) in LDS as
// float4{x,y,z,sq}. Inner: key = fma(mx,qx, fma(my,qy, fma(mz,qz, q.sq))),
// 4-deep unroll (4 outstanding broadcast ds_read_b128 per iteration).
// Writes per-own-point partials (coalesced), no atomics, no ws init.
// ---------------------------------------------------------------------------
__global__ __launch_bounds__(TB) void chamfer_kernel(
    const float* __restrict__ y_pred,
    const float* __restrict__ sp,
    float* __restrict__ ws)
{
    __shared__ __align__(16) float4 pts[SCH];   // 8 KB

    const int blk = blockIdx.x;
    const int bh  = blk >> 2;
    const int oh  = (blk >> 1) & 1;
    const int sh  = blk & 1;
    const int b   = bh >> 4;            // HH = 16
    const int tid = threadIdx.x;

    float pnx = y_pred[bh * 4 + 0];
    float pny = y_pred[bh * 4 + 1];
    float pnz = y_pred[bh * 4 + 2];
    float pd  = y_pred[bh * 4 + 3];
    float inv = 1.0f / sqrtf(pnx * pnx + pny * pny + pnz * pnz);
    pnx *= inv; pny *= inv; pnz *= inv;

    const float* spb = sp + (size_t)b * NN * 3;

    // stage scan half: raw samples with squared norm
    for (int k = tid; k < SCH; k += TB) {
        int j = sh * SCH + k;
        float x = spb[j * 3 + 0], y = spb[j * 3 + 1], z = spb[j * 3 + 2];
        pts[k] = make_float4(x, y, z, x * x + y * y + z * z);
    }

    // own points: reflected, pre-scaled by -2
    float mx[POWN], my[POWN], mz[POWN], osq[POWN];
#pragma unroll
    for (int u = 0; u < POWN; ++u) {
        int i = oh * OCH + u * TB + tid;
        float x = spb[i * 3 + 0], y = spb[i * 3 + 1], z = spb[i * 3 + 2];
        float proj = x * pnx + y * pny + z * pnz + pd;
        x -= 2.0f * proj * pnx;
        y -= 2.0f * proj * pny;
        z -= 2.0f * proj * pnz;
        osq[u] = x * x + y * y + z * z;
        mx[u] = -2.0f * x; my[u] = -2.0f * y; mz[u] = -2.0f * z;
    }
    __syncthreads();

    float m0[POWN], m1[POWN], m2[POWN], m3[POWN];
#pragma unroll
    for (int u = 0; u < POWN; ++u) { m0[u] = 3.4e38f; m1[u] = 3.4e38f; m2[u] = 3.4e38f; m3[u] = 3.4e38f; }

    for (int j = 0; j < SCH; j += 4) {
        float4 qa = pts[j + 0];
        float4 qb = pts[j + 1];
        float4 qc = pts[j + 2];
        float4 qd = pts[j + 3];
#pragma unroll
        for (int u = 0; u < POWN; ++u) {
            m0[u] = fminf(m0[u], fmaf(mx[u], qa.x, fmaf(my[u], qa.y, fmaf(mz[u], qa.z, qa.w))));
            m1[u] = fminf(m1[u], fmaf(mx[u], qb.x, fmaf(my[u], qb.y, fmaf(mz[u], qb.z, qb.w))));
            m2[u] = fminf(m2[u], fmaf(mx[u], qc.x, fmaf(my[u], qc.y, fmaf(mz[u], qc.z, qc.w))));
            m3[u] = fminf(m3[u], fmaf(mx[u], qd.x, fmaf(my[u], qd.y, fmaf(mz[u], qd.z, qd.w))));
        }
    }

    float* wp = ws + ((size_t)(bh * 2 + sh)) * NN + oh * OCH;
#pragma unroll
    for (int u = 0; u < POWN; ++u)
        wp[u * TB + tid] = osq[u] + fminf(fminf(m0[u], m1[u]), fminf(m2[u], m3[u]));
}

// ---------------------------------------------------------------------------
// finalize (per batch, 256 threads): centroid; sde[h] = 2/N * sum_i
// min(part[h][0][i], part[h][1][i]); conf; angle-NMS; stable rank; write.
// ---------------------------------------------------------------------------
__global__ __launch_bounds__(TB) void finalize_kernel(
    const float* __restrict__ ws,
    const float* __restrict__ y_pred,
    const float* __restrict__ sp,
    float* __restrict__ out)
{
    const int b   = blockIdx.x;
    const int tid = threadIdx.x;

    __shared__ float sde_s[HH], nx_s[HH], ny_s[HH], nz_s[HH], d_s[HH], conf_s[HH];
    __shared__ float cmacc[3];
    __shared__ int keep_s[HH];

    if (tid < HH) sde_s[tid] = 0.0f;
    if (tid < 3)  cmacc[tid] = 0.0f;
    __syncthreads();

    // centroid: 1024 samples over 256 threads
    const float* spb = sp + (size_t)b * NN * 3;
    float sx = 0.0f, sy = 0.0f, sz = 0.0f;
    for (int p = tid; p < NN; p += TB) {
        sx += spb[p * 3 + 0];
        sy += spb[p * 3 + 1];
        sz += spb[p * 3 + 2];
    }
    for (int off = 32; off; off >>= 1) {
        sx += __shfl_down(sx, off, 64);
        sy += __shfl_down(sy, off, 64);
        sz += __shfl_down(sz, off, 64);
    }
    if ((tid & 63) == 0) {
        atomicAdd(&cmacc[0], sx);
        atomicAdd(&cmacc[1], sy);
        atomicAdd(&cmacc[2], sz);
    }

    // sde accumulation: 16 threads per h, each covers 64 i's
    {
        const int h   = tid >> 4;
        const int sub = tid & 15;
        const float* p0 = ws + ((size_t)((b * HH + h) * 2 + 0)) * NN;
        const float* p1 = ws + ((size_t)((b * HH + h) * 2 + 1)) * NN;
        float acc = 0.0f;
        for (int k = 0; k < 64; ++k) {
            int i = sub * 64 + k;
            acc += fminf(p0[i], p1[i]);
        }
        atomicAdd(&sde_s[h], acc);
    }
    __syncthreads();

    const float cmx = cmacc[0] / NN, cmy = cmacc[1] / NN, cmz = cmacc[2] / NN;

    if (tid < HH) {
        int h = tid;
        float nx = y_pred[(b * HH + h) * 4 + 0];
        float ny = y_pred[(b * HH + h) * 4 + 1];
        float nz = y_pred[(b * HH + h) * 4 + 2];
        float d  = y_pred[(b * HH + h) * 4 + 3];
        float inv = 1.0f / sqrtf(nx * nx + ny * ny + nz * nz);
        nx *= inv; ny *= inv; nz *= inv;
        nx_s[h] = nx; ny_s[h] = ny; nz_s[h] = nz; d_s[h] = d;
        sde_s[h] = sde_s[h] * (2.0f / NN);     // both chamfer terms are equal
    }
    __syncthreads();

    if (tid < HH) {
        int h = tid;
        float mn = sde_s[0], mx = sde_s[0];
        for (int g = 1; g < HH; ++g) {
            mn = fminf(mn, sde_s[g]);
            mx = fmaxf(mx, sde_s[g]);
        }
        float sde  = sde_s[h];
        float conf = 1.0f - (sde - mn) / fabsf(mx - mn);
        conf_s[h]  = conf;
        bool valid = (sde <= 10.0f);
        bool sup   = false;
        if (valid) {
            for (int g = 0; g < HH; ++g) {
                if (g == h) continue;
                float c = nx_s[h] * nx_s[g] + ny_s[h] * ny_s[g] + nz_s[h] * nz_s[g];
                c = fminf(1.0f, fmaxf(-1.0f, c));
                float ang = acosf(c) * 57.29577951308232f;
                bool close = (ang < 30.0f) || (180.0f - ang < 30.0f);
                if (close && (sde_s[g] <= 10.0f) && (sde >= sde_s[g])) sup = true;
            }
        }
        keep_s[h] = (valid && !sup) ? 1 : 0;
    }
    __syncthreads();

    if (tid < HH) {
        int h = tid;
        // stable descending rank on key = keep ? conf : -inf (jnp.argsort(-key))
        float keyh = keep_s[h] ? conf_s[h] : -INFINITY;
        int pos = 0;
        for (int g = 0; g < HH; ++g) {
            float keyg = keep_s[g] ? conf_s[g] : -INFINITY;
            if (keyg > keyh || (keyg == keyh && g < h)) ++pos;
        }
        float nx = nx_s[h], ny = ny_s[h], nz = nz_s[h];
        float t  = nx * cmx + ny * cmy + nz * cmz + d_s[h];
        float px = cmx - t * nx, py = cmy - t * ny, pz = cmz - t * nz;

        float* o = out + (size_t)(b * HH + pos) * 8;
        if (keep_s[h]) {
            o[0] = nx; o[1] = ny; o[2] = nz;
            o[3] = px; o[4] = py; o[5] = pz;
            o[6] = conf_s[h];
            o[7] = sde_s[h];
        } else {
            for (int c = 0; c < 8; ++c) o[c] = 0.0f;
        }
    }
}

extern "C" void kernel_launch(void* const* d_in, const int* in_sizes, int n_in,
                              void* d_out, int out_size, void* d_ws, size_t ws_size,
                              hipStream_t stream) {
    const float* y_pred = (const float*)d_in[0];   // (8,16,4) f32
    const float* sp     = (const float*)d_in[1];   // (8,1024,3) f32
    float* out          = (float*)d_out;           // (8,16,8) f32
    float* ws           = (float*)d_ws;            // 1 MB partials, all written

    chamfer_kernel<<<dim3(BB * HH * 4), dim3(TB), 0, stream>>>(y_pred, sp, ws);
    finalize_kernel<<<dim3(BB), dim3(TB), 0, stream>>>(ws, y_pred, sp, out);
}